// Round 14
// baseline (337.030 us; speedup 1.0000x reference)
//
#include <hip/hip_runtime.h>
#include <hip/hip_fp16.h>

#define N_NODES 100000
#define N_EDGES 1600000
#define E_TOT   (N_EDGES + N_NODES)
#define NEG_SLOPE 0.2f

#define BSH   9
#define BSZ   512                         // nodes per bucket
#define NBKT  ((N_NODES + BSZ - 1) / BSZ) // 196
#define CAP   16384                       // padded bucket capacity (pow2, line-aligned resv)
#define EPB   2048                        // edges per partition block
#define PART_B ((E_TOT + EPB - 1) / EPB)  // 831
#define GEMM1_B ((N_NODES + 63) / 64)     // 1563
#define GSTRIDE 16                        // gcur padding: 1 cache line / bucket

typedef _Float16 half8_t __attribute__((ext_vector_type(8)));
typedef float f32x4 __attribute__((ext_vector_type(4)));

__device__ __forceinline__ float lrelu(float v) { return v > 0.f ? v : NEG_SLOPE * v; }

__device__ __forceinline__ float f16lo(unsigned u) {
    return __half2float(__ushort_as_half((unsigned short)(u & 0xFFFFu)));
}
__device__ __forceinline__ float f16hi(unsigned u) {
    return __half2float(__ushort_as_half((unsigned short)(u >> 16)));
}

// ---- prep: W1^T -> fp16 global (k contiguous per col) + padded gcur zero ----
__global__ __launch_bounds__(256) void k_prep(const float* __restrict__ W1,
                                              _Float16* __restrict__ w1t,
                                              int* __restrict__ gcur) {
    int idx = blockIdx.x * 256 + threadIdx.x;     // [0, 4096)
    if (idx < NBKT * GSTRIDE) gcur[idx] = 0;
    int k = idx >> 5;
    int c0 = (idx & 31) * 4;
    float4 wv = ((const float4*)W1)[idx];
    w1t[(c0 + 0) * 128 + k] = (_Float16)wv.x;
    w1t[(c0 + 1) * 128 + k] = (_Float16)wv.y;
    w1t[(c0 + 2) * 128 + k] = (_Float16)wv.z;
    w1t[(c0 + 3) * 128 + k] = (_Float16)wv.w;
}

// ---- edge partition: line-aligned per-(block,bucket) reservations ----
// Each reservation is rounded up to 16 ints (one 64B line) so no cache line of
// packed[] is ever shared between blocks (kills cross-XCD write-allocate
// ping-pong). Pad slots hold -1 sentinels; k_build skips them.
__global__ __launch_bounds__(256) void k_part(const int* __restrict__ ei,
                                              int* __restrict__ gcur,
                                              int* __restrict__ packed) {
    __shared__ int lcnt[NBKT];
    __shared__ int gpos[NBKT];
    __shared__ int lcur[NBKT];
    int t = threadIdx.x;
    int se[8], de[8];
    size_t base = (size_t)blockIdx.x * EPB;
#pragma unroll
    for (int i = 0; i < 8; ++i) {
        size_t e = base + t + i * 256;
        if (e < E_TOT) {
            if (e < N_EDGES) { se[i] = ei[e]; de[i] = ei[N_EDGES + e]; }
            else             { se[i] = (int)(e - N_EDGES); de[i] = se[i]; }
        } else de[i] = -1;
    }
    for (int i = t; i < NBKT; i += 256) lcnt[i] = 0;
    __syncthreads();
#pragma unroll
    for (int i = 0; i < 8; ++i)
        if (de[i] >= 0) atomicAdd(&lcnt[de[i] >> BSH], 1);
    __syncthreads();
    for (int i = t; i < NBKT; i += 256) {
        int c = lcnt[i];
        int res = (c + 15) & ~15;            // line-aligned reservation
        gpos[i] = c ? (i * CAP + atomicAdd(&gcur[i * GSTRIDE], res)) : 0;
        lcur[i] = 0;
    }
    __syncthreads();
#pragma unroll
    for (int i = 0; i < 8; ++i) {
        if (de[i] >= 0) {
            int b = de[i] >> BSH;
            int c = atomicAdd(&lcur[b], 1);
            packed[gpos[b] + c] = ((de[i] & (BSZ - 1)) << 17) | se[i];
        }
    }
    __syncthreads();
    // fill pad slots with sentinel so every reserved line is fully written here
    for (int i = t; i < NBKT; i += 256) {
        int c = lcnt[i];
        if (c) {
            int res = (c + 15) & ~15;
            for (int j = c; j < res; ++j) packed[gpos[i] + j] = -1;
        }
    }
}

// ---- MFMA layer-1 GEMM: h1(fp16) = x @ W1, fused attention logits ----
__global__ __launch_bounds__(256) void k_gemm1(
        const float* __restrict__ x, const _Float16* __restrict__ w1t,
        const float* __restrict__ a_src, const float* __restrict__ a_dst,
        unsigned short* __restrict__ h1h, float* __restrict__ als,
        float* __restrict__ ald) {
    __shared__ __align__(16) _Float16 cs[64 * 136];   // 17.4 KB C tile
    int t = threadIdx.x;
    int nb = blockIdx.x * 64;
    int wv = t >> 6, lane = t & 63;
    int mn = lane & 15, quad = lane >> 4;
    int an = nb + wv * 16 + mn;
    if (an >= N_NODES) an = 0;                 // clamp (output guarded later)
    const float* xrow = x + (size_t)an * 128;
    f32x4 acc[8];
#pragma unroll
    for (int ct = 0; ct < 8; ++ct) acc[ct] = (f32x4){0.f, 0.f, 0.f, 0.f};
#pragma unroll
    for (int kk = 0; kk < 4; ++kk) {
        float4 a0 = *(const float4*)(xrow + kk * 32 + quad * 8);
        float4 a1 = *(const float4*)(xrow + kk * 32 + quad * 8 + 4);
        half8_t af = { (_Float16)a0.x, (_Float16)a0.y, (_Float16)a0.z, (_Float16)a0.w,
                       (_Float16)a1.x, (_Float16)a1.y, (_Float16)a1.z, (_Float16)a1.w };
#pragma unroll
        for (int ct = 0; ct < 8; ++ct) {
            half8_t bf = *(const half8_t*)(w1t + (ct * 16 + mn) * 128 + kk * 32 + quad * 8);
            acc[ct] = __builtin_amdgcn_mfma_f32_16x16x32_f16(af, bf, acc[ct], 0, 0, 0);
        }
    }
    // C layout: col = lane&15, row = quad*4 + reg -> LDS (2-way banks max)
#pragma unroll
    for (int ct = 0; ct < 8; ++ct)
#pragma unroll
        for (int r = 0; r < 4; ++r) {
            int nl = wv * 16 + quad * 4 + r;
            cs[nl * 136 + ct * 16 + mn] = (_Float16)acc[ct][r];
        }
    __syncthreads();
    // epilogue: thread (node=t>>2, seg=t&3): 64B h-row segment -> global + logits
    int node = t >> 2, seg = t & 3;
    int gn = nb + node;
    if (gn < N_NODES) {
        const half8_t* hp = (const half8_t*)&cs[node * 136 + seg * 32];
        uint4* gout = (uint4*)(h1h + (size_t)gn * 128 + seg * 32);
        const float4* asp = (const float4*)a_src;
        const float4* adp = (const float4*)a_dst;
        float vs = 0.f, vd = 0.f;
#pragma unroll
        for (int jj = 0; jj < 4; ++jj) {
            half8_t hv = hp[jj];
            gout[jj] = *(const uint4*)&hv;
            float4 aS0 = asp[seg * 8 + jj * 2], aS1 = asp[seg * 8 + jj * 2 + 1];
            float4 aD0 = adp[seg * 8 + jj * 2], aD1 = adp[seg * 8 + jj * 2 + 1];
            vs += (float)hv[0] * aS0.x + (float)hv[1] * aS0.y + (float)hv[2] * aS0.z + (float)hv[3] * aS0.w
                + (float)hv[4] * aS1.x + (float)hv[5] * aS1.y + (float)hv[6] * aS1.z + (float)hv[7] * aS1.w;
            vd += (float)hv[0] * aD0.x + (float)hv[1] * aD0.y + (float)hv[2] * aD0.z + (float)hv[3] * aD0.w
                + (float)hv[4] * aD1.x + (float)hv[5] * aD1.y + (float)hv[6] * aD1.z + (float)hv[7] * aD1.w;
        }
        als[gn * 4 + seg] = vs;
        ald[gn * 4 + seg] = vd;
    }
}

// ---- per-bucket: count (skip sentinels), scan -> rowptr+deg, col scatter ----
__global__ __launch_bounds__(512) void k_build(const int* __restrict__ packed,
                                               const int* __restrict__ gcur,
                                               int* __restrict__ rowptr,
                                               int* __restrict__ deg,
                                               int* __restrict__ col) {
    int t = threadIdx.x;
    int b = blockIdx.x;
    int nb = b << BSH;
    int ebeg = b * CAP;
    int eend = ebeg + gcur[b * GSTRIDE];
    __shared__ int cnt[BSZ];
    __shared__ int ps[BSZ];
    cnt[t] = 0;
    __syncthreads();
    for (int i = ebeg + t; i < eend; i += 512) {
        int p = packed[i];
        if (p >= 0) atomicAdd(&cnt[p >> 17], 1);
    }
    __syncthreads();
    int v = cnt[t];
    ps[t] = v;
    __syncthreads();
    for (int off = 1; off < 512; off <<= 1) {
        int u = (t >= off) ? ps[t - off] : 0;
        __syncthreads();
        ps[t] += u;
        __syncthreads();
    }
    int myofs = ebeg + ps[t] - v;
    int n = nb + t;
    if (n < N_NODES) { rowptr[n] = myofs; deg[n] = v; }
    __syncthreads();
    cnt[t] = myofs;
    __syncthreads();
    for (int i = ebeg + t; i < eend; i += 512) {
        int p = packed[i];
        if (p >= 0) {
            int pos = atomicAdd(&cnt[p >> 17], 1);
            col[pos] = p & 0x1FFFF;
        }
    }
}

// ---- Layer 1 aggregation: wave/node, 4 edges/iter uint4 row gathers ----
__global__ __launch_bounds__(256) void k_agg1(const unsigned short* __restrict__ h1h,
                                              const float* __restrict__ als,
                                              const float* __restrict__ ald,
                                              const int* __restrict__ rowptr,
                                              const int* __restrict__ deg,
                                              const int* __restrict__ col,
                                              const float* __restrict__ b1,
                                              float* __restrict__ out1) {
    __shared__ float sex_all[4][64 * 4];
    __shared__ int   scol_all[4][64];
    int w = threadIdx.x >> 6;
    int lane = threadIdx.x & 63;
    int n = blockIdx.x * 4 + w;
    int slot = lane >> 4, cg = lane & 15;
    int hd = cg >> 2;
    float* sex = sex_all[w];
    int* scol = scol_all[w];
    float4 ald4 = ((const float4*)ald)[n];
    int beg = rowptr[n], dtot = deg[n];
    float a0 = 0.f, a1 = 0.f, a2 = 0.f, a3 = 0.f;
    float a4 = 0.f, a5 = 0.f, a6 = 0.f, a7 = 0.f, den = 0.f;
    const float4* als4p = (const float4*)als;
    for (int base = 0; base < dtot; base += 64) {
        int cnt = min(64, dtot - base);
        int myc = 0;
        if (lane < cnt) myc = col[beg + base + lane];
        __asm__ volatile("s_waitcnt lgkmcnt(0)" ::: "memory");
        if (lane < cnt) {
            scol[lane] = myc;
            float4 as4 = als4p[myc];
            float4 e4;
            e4.x = __expf(lrelu(as4.x + ald4.x));
            e4.y = __expf(lrelu(as4.y + ald4.y));
            e4.z = __expf(lrelu(as4.z + ald4.z));
            e4.w = __expf(lrelu(as4.w + ald4.w));
            ((float4*)sex)[lane] = e4;
        }
        __asm__ volatile("s_waitcnt lgkmcnt(0)" ::: "memory");
#pragma unroll 2
        for (int q4 = 0; q4 < cnt; q4 += 4) {
            int myq = q4 + slot;
            int cq = min(myq, cnt - 1);
            int s = scol[cq];
            float ex = (myq < cnt) ? sex[cq * 4 + hd] : 0.f;
            uint4 hv = *(const uint4*)((const char*)h1h + (((size_t)s << 8) + (cg << 4)));
            a0 = fmaf(ex, f16lo(hv.x), a0);
            a1 = fmaf(ex, f16hi(hv.x), a1);
            a2 = fmaf(ex, f16lo(hv.y), a2);
            a3 = fmaf(ex, f16hi(hv.y), a3);
            a4 = fmaf(ex, f16lo(hv.z), a4);
            a5 = fmaf(ex, f16hi(hv.z), a5);
            a6 = fmaf(ex, f16lo(hv.w), a6);
            a7 = fmaf(ex, f16hi(hv.w), a7);
            den += ex;
        }
    }
    a0 += __shfl_xor(a0, 16, 64); a1 += __shfl_xor(a1, 16, 64);
    a2 += __shfl_xor(a2, 16, 64); a3 += __shfl_xor(a3, 16, 64);
    a4 += __shfl_xor(a4, 16, 64); a5 += __shfl_xor(a5, 16, 64);
    a6 += __shfl_xor(a6, 16, 64); a7 += __shfl_xor(a7, 16, 64);
    den += __shfl_xor(den, 16, 64);
    a0 += __shfl_xor(a0, 32, 64); a1 += __shfl_xor(a1, 32, 64);
    a2 += __shfl_xor(a2, 32, 64); a3 += __shfl_xor(a3, 32, 64);
    a4 += __shfl_xor(a4, 32, 64); a5 += __shfl_xor(a5, 32, 64);
    a6 += __shfl_xor(a6, 32, 64); a7 += __shfl_xor(a7, 32, 64);
    den += __shfl_xor(den, 32, 64);
    if (lane < 16) {
        float inv = 1.0f / den;
        float4 bA = ((const float4*)b1)[2 * lane];
        float4 bB = ((const float4*)b1)[2 * lane + 1];
        float4 oA, oB;
        oA.x = fmaxf(fmaf(a0, inv, bA.x), 0.f);
        oA.y = fmaxf(fmaf(a1, inv, bA.y), 0.f);
        oA.z = fmaxf(fmaf(a2, inv, bA.z), 0.f);
        oA.w = fmaxf(fmaf(a3, inv, bA.w), 0.f);
        oB.x = fmaxf(fmaf(a4, inv, bB.x), 0.f);
        oB.y = fmaxf(fmaf(a5, inv, bB.y), 0.f);
        oB.z = fmaxf(fmaf(a6, inv, bB.z), 0.f);
        oB.w = fmaxf(fmaf(a7, inv, bB.w), 0.f);
        ((float4*)out1)[(size_t)n * 32 + 2 * lane]     = oA;
        ((float4*)out1)[(size_t)n * 32 + 2 * lane + 1] = oB;
    }
}

// ---- Layer 2 GEMM: h2(fp16) = out1 @ W2, fused logits ----
__global__ __launch_bounds__(256) void k_gemm2(const float* __restrict__ out1,
                                               const float* __restrict__ W2,
                                               const float* __restrict__ a_src,
                                               const float* __restrict__ a_dst,
                                               unsigned short* __restrict__ h2h,
                                               float* __restrict__ als,
                                               float* __restrict__ ald) {
    __shared__ float W2s[128 * 16];
    __shared__ float xs[16 * 132];
    int t = threadIdx.x;
#pragma unroll
    for (int i = 0; i < 8; ++i) W2s[t + i * 256] = W2[t + i * 256];
    size_t base = (size_t)blockIdx.x * 16 * 128;
#pragma unroll
    for (int i = 0; i < 8; ++i) {
        int idx = t + i * 256;
        xs[(idx >> 7) * 132 + (idx & 127)] = out1[base + idx];
    }
    __syncthreads();
    int r = t >> 4, c = t & 15;
    float acc = 0.f;
    const float* xr = &xs[r * 132];
#pragma unroll 8
    for (int k = 0; k < 128; ++k) acc = fmaf(xr[k], W2s[k * 16 + c], acc);
    int n = blockIdx.x * 16 + r;
    h2h[(size_t)n * 16 + c] = __half_as_ushort(__float2half(acc));
    float vs = acc * a_src[c];
    float vd = acc * a_dst[c];
#pragma unroll
    for (int off = 8; off >= 1; off >>= 1) {
        vs += __shfl_down(vs, off, 16);
        vd += __shfl_down(vd, off, 16);
    }
    if (c == 0) { als[n] = vs; ald[n] = vd; }
}

// ---- Layer 2 aggregation: wave/node, 16 edges/iter, batched exp in LDS ----
__global__ __launch_bounds__(256) void k_agg2(const unsigned short* __restrict__ h2h,
                                              const float* __restrict__ als,
                                              const float* __restrict__ ald,
                                              const int* __restrict__ rowptr,
                                              const int* __restrict__ deg,
                                              const int* __restrict__ col,
                                              const float* __restrict__ b2,
                                              float* __restrict__ out) {
    __shared__ float sex_all[4][64];
    __shared__ int   scol_all[4][64];
    int w = threadIdx.x >> 6;
    int lane = threadIdx.x & 63;
    int n = blockIdx.x * 4 + w;
    int slot = lane >> 2, q = lane & 3;
    float* sex = sex_all[w];
    int* scol = scol_all[w];
    float ad = ald[n];
    int beg = rowptr[n], dtot = deg[n];
    float a0 = 0.f, a1 = 0.f, a2 = 0.f, a3 = 0.f, den = 0.f;
    for (int base = 0; base < dtot; base += 64) {
        int cnt = min(64, dtot - base);
        int myc = 0;
        if (lane < cnt) myc = col[beg + base + lane];
        __asm__ volatile("s_waitcnt lgkmcnt(0)" ::: "memory");
        if (lane < cnt) {
            scol[lane] = myc;
            sex[lane] = __expf(lrelu(als[myc] + ad));
        }
        __asm__ volatile("s_waitcnt lgkmcnt(0)" ::: "memory");
#pragma unroll 2
        for (int q16 = 0; q16 < cnt; q16 += 16) {
            int myq = q16 + slot;
            int cq = min(myq, cnt - 1);
            int s = scol[cq];
            float ex = (myq < cnt) ? sex[cq] : 0.f;
            uint2 hv = *(const uint2*)((const char*)h2h + ((size_t)s * 32u + (q << 3)));
            a0 = fmaf(ex, f16lo(hv.x), a0);
            a1 = fmaf(ex, f16hi(hv.x), a1);
            a2 = fmaf(ex, f16lo(hv.y), a2);
            a3 = fmaf(ex, f16hi(hv.y), a3);
            den += ex;
        }
    }
#pragma unroll
    for (int off = 4; off <= 32; off <<= 1) {
        a0 += __shfl_xor(a0, off, 64);
        a1 += __shfl_xor(a1, off, 64);
        a2 += __shfl_xor(a2, off, 64);
        a3 += __shfl_xor(a3, off, 64);
        den += __shfl_xor(den, off, 64);
    }
    if (slot == 0) {
        float inv = 1.0f / den;
        float4 b4 = ((const float4*)b2)[q];
        float4 o;
        o.x = fmaf(a0, inv, b4.x);
        o.y = fmaf(a1, inv, b4.y);
        o.z = fmaf(a2, inv, b4.z);
        o.w = fmaf(a3, inv, b4.w);
        ((float4*)out)[(size_t)n * 4 + q] = o;
    }
}

extern "C" void kernel_launch(void* const* d_in, const int* in_sizes, int n_in,
                              void* d_out, int out_size, void* d_ws, size_t ws_size,
                              hipStream_t stream) {
    const float* x   = (const float*)d_in[0];
    const int*   ei  = (const int*)d_in[1];
    const float* W1  = (const float*)d_in[2];
    const float* as1 = (const float*)d_in[3];
    const float* ad1 = (const float*)d_in[4];
    const float* b1  = (const float*)d_in[5];
    const float* W2  = (const float*)d_in[6];
    const float* as2 = (const float*)d_in[7];
    const float* ad2 = (const float*)d_in[8];
    const float* b2  = (const float*)d_in[9];
    float* out = (float*)d_out;

    char* ws = (char*)d_ws;
    size_t off = 0;
    auto alloc = [&](size_t bytes) -> void* {
        void* p = ws + off;
        off += (bytes + 255) & ~(size_t)255;
        return p;
    };
    unsigned short* h1h = (unsigned short*)alloc((size_t)N_NODES * 128 * 2);
    float* out1  = (float*)alloc((size_t)N_NODES * 128 * 4);
    float* als1v = (float*)alloc((size_t)N_NODES * 4 * 4);
    float* ald1v = (float*)alloc((size_t)N_NODES * 4 * 4);
    unsigned short* h2h = (unsigned short*)alloc((size_t)N_NODES * 16 * 2);
    float* als2v = (float*)alloc((size_t)N_NODES * 4);
    float* ald2v = (float*)alloc((size_t)N_NODES * 4);
    int* rowptr  = (int*)alloc((size_t)N_NODES * 4);
    int* degv    = (int*)alloc((size_t)N_NODES * 4);
    int* gcur    = (int*)alloc((size_t)NBKT * GSTRIDE * 4);
    _Float16* w1t = (_Float16*)alloc((size_t)128 * 128 * 2);
    int* packed  = (int*)alloc((size_t)NBKT * CAP * 4);
    int* colA    = (int*)alloc((size_t)NBKT * CAP * 4);

    k_prep<<<16, 256, 0, stream>>>(W1, w1t, gcur);
    k_part<<<PART_B, 256, 0, stream>>>(ei, gcur, packed);
    k_gemm1<<<GEMM1_B, 256, 0, stream>>>(x, w1t, as1, ad1, h1h, als1v, ald1v);
    k_build<<<NBKT, 512, 0, stream>>>(packed, gcur, rowptr, degv, colA);
    k_agg1<<<N_NODES / 4, 256, 0, stream>>>(h1h, als1v, ald1v, rowptr, degv, colA, b1, out1);
    k_gemm2<<<N_NODES / 16, 256, 0, stream>>>(out1, W2, as2, ad2, h2h, als2v, ald2v);
    k_agg2<<<N_NODES / 4, 256, 0, stream>>>(h2h, als2v, ald2v, rowptr, degv, colA, b2, out);
}

// Round 15
// 318.542 us; speedup vs baseline: 1.0580x; 1.0580x over previous
//
#include <hip/hip_runtime.h>
#include <hip/hip_fp16.h>

#define N_NODES 100000
#define N_EDGES 1600000
#define E_TOT   (N_EDGES + N_NODES)
#define NEG_SLOPE 0.2f

#define BSH   9
#define BSZ   512                         // nodes per bucket
#define NBKT  ((N_NODES + BSZ - 1) / BSZ) // 196
#define CAP   10240                       // padded bucket capacity (mean 8673)
#define EPB   2048                        // edges per partition block
#define PART_B ((E_TOT + EPB - 1) / EPB)  // 831
#define PREP_B 16
#define GEMM1_B ((N_NODES + 63) / 64)     // 1563
#define GSTRIDE 16                        // gcur padding: 1 cache line / bucket

typedef _Float16 half8_t __attribute__((ext_vector_type(8)));
typedef float f32x4 __attribute__((ext_vector_type(4)));

__device__ __forceinline__ float lrelu(float v) { return v > 0.f ? v : NEG_SLOPE * v; }

__device__ __forceinline__ float f16lo(unsigned u) {
    return __half2float(__ushort_as_half((unsigned short)(u & 0xFFFFu)));
}
__device__ __forceinline__ float f16hi(unsigned u) {
    return __half2float(__ushort_as_half((unsigned short)(u >> 16)));
}

// ---- Launch 1: [prep role: W1^T -> fp16 global] | [part role: bucket edges] ----
// prep feeds gemm1 (next launch); part feeds build (next launch). Independent.
__global__ __launch_bounds__(256) void k_prep_part(
        const float* __restrict__ W1, _Float16* __restrict__ w1t,
        const int* __restrict__ ei, int* __restrict__ gcur,
        int* __restrict__ packed) {
    __shared__ int lcnt[NBKT];
    __shared__ int gpos[NBKT];
    __shared__ int lcur[NBKT];
    int t = threadIdx.x;
    if (blockIdx.x < PREP_B) {
        // ---- prep role: transpose W1 to fp16 (k contiguous per out-col) ----
        int idx = blockIdx.x * 256 + t;               // [0, 4096)
        int k = idx >> 5;
        int c0 = (idx & 31) * 4;
        float4 wv = ((const float4*)W1)[idx];
        w1t[(c0 + 0) * 128 + k] = (_Float16)wv.x;
        w1t[(c0 + 1) * 128 + k] = (_Float16)wv.y;
        w1t[(c0 + 2) * 128 + k] = (_Float16)wv.z;
        w1t[(c0 + 3) * 128 + k] = (_Float16)wv.w;
        return;
    }
    // ---- part role: register-cached edges, LDS histogram, bucket scatter ----
    int se[8], de[8];
    size_t base = (size_t)(blockIdx.x - PREP_B) * EPB;
#pragma unroll
    for (int i = 0; i < 8; ++i) {
        size_t e = base + t + i * 256;
        if (e < E_TOT) {
            if (e < N_EDGES) { se[i] = ei[e]; de[i] = ei[N_EDGES + e]; }
            else             { se[i] = (int)(e - N_EDGES); de[i] = se[i]; }
        } else de[i] = -1;
    }
    for (int i = t; i < NBKT; i += 256) lcnt[i] = 0;
    __syncthreads();
#pragma unroll
    for (int i = 0; i < 8; ++i)
        if (de[i] >= 0) atomicAdd(&lcnt[de[i] >> BSH], 1);
    __syncthreads();
    for (int i = t; i < NBKT; i += 256) {
        int c = lcnt[i];
        gpos[i] = c ? (i * CAP + atomicAdd(&gcur[i * GSTRIDE], c)) : 0;
        lcur[i] = 0;
    }
    __syncthreads();
#pragma unroll
    for (int i = 0; i < 8; ++i) {
        if (de[i] >= 0) {
            int b = de[i] >> BSH;
            int c = atomicAdd(&lcur[b], 1);
            packed[gpos[b] + c] = ((de[i] & (BSZ - 1)) << 17) | se[i];
        }
    }
}

// ---- Launch 2: [build role: packed -> rowptr/deg/col] | [MFMA gemm1 role] ----
// build needs packed (L1 part); gemm1 needs w1t (L1 prep). Independent of each
// other -> co-launched; build's 196 latency-bound blocks hide under gemm1.
__global__ __launch_bounds__(256) void k_gemm1_build(
        const float* __restrict__ x, const _Float16* __restrict__ w1t,
        const float* __restrict__ a_src, const float* __restrict__ a_dst,
        unsigned short* __restrict__ h1h, float* __restrict__ als,
        float* __restrict__ ald,
        const int* __restrict__ packed, const int* __restrict__ gcur,
        int* __restrict__ rowptr, int* __restrict__ deg, int* __restrict__ col) {
    __shared__ __align__(16) union {
        _Float16 cs[64 * 136];                    // 17.4 KB gemm1 C tile
        struct { int cnt[BSZ]; int ps[256]; } b;  // build role
    } sm;
    int t = threadIdx.x;
    if (blockIdx.x < NBKT) {
        // ---------------- build role (256 threads, 2 nodes/thread) ----------------
        int b = blockIdx.x;
        int nb = b << BSH;
        int ebeg = b * CAP;
        int eend = ebeg + gcur[b * GSTRIDE];
        sm.b.cnt[t] = 0;
        sm.b.cnt[t + 256] = 0;
        __syncthreads();
        for (int i = ebeg + t; i < eend; i += 256)
            atomicAdd(&sm.b.cnt[packed[i] >> 17], 1);
        __syncthreads();
        int v0 = sm.b.cnt[2 * t], v1 = sm.b.cnt[2 * t + 1];
        int s = v0 + v1;
        sm.b.ps[t] = s;
        __syncthreads();
        for (int off = 1; off < 256; off <<= 1) {
            int u = (t >= off) ? sm.b.ps[t - off] : 0;
            __syncthreads();
            sm.b.ps[t] += u;
            __syncthreads();
        }
        int base = ebeg + sm.b.ps[t] - s;         // exclusive offset of node 2t
        int n0 = nb + 2 * t, n1 = nb + 2 * t + 1;
        if (n0 < N_NODES) { rowptr[n0] = base;      deg[n0] = v0; }
        if (n1 < N_NODES) { rowptr[n1] = base + v0; deg[n1] = v1; }
        sm.b.cnt[2 * t]     = base;                // cursors (each slot owned by t)
        sm.b.cnt[2 * t + 1] = base + v0;
        __syncthreads();
        for (int i = ebeg + t; i < eend; i += 256) {
            int p = packed[i];
            int pos = atomicAdd(&sm.b.cnt[p >> 17], 1);
            col[pos] = p & 0x1FFFF;
        }
        return;
    }
    // ---------------- gemm1 role: h1 = x @ W1 via fp16 MFMA ----------------
    int nb = (blockIdx.x - NBKT) * 64;
    int wv = t >> 6, lane = t & 63;
    int mn = lane & 15, quad = lane >> 4;
    int an = nb + wv * 16 + mn;
    if (an >= N_NODES) an = 0;                 // clamp (output guarded later)
    const float* xrow = x + (size_t)an * 128;
    f32x4 acc[8];
#pragma unroll
    for (int ct = 0; ct < 8; ++ct) acc[ct] = (f32x4){0.f, 0.f, 0.f, 0.f};
#pragma unroll
    for (int kk = 0; kk < 4; ++kk) {
        float4 a0 = *(const float4*)(xrow + kk * 32 + quad * 8);
        float4 a1 = *(const float4*)(xrow + kk * 32 + quad * 8 + 4);
        half8_t af = { (_Float16)a0.x, (_Float16)a0.y, (_Float16)a0.z, (_Float16)a0.w,
                       (_Float16)a1.x, (_Float16)a1.y, (_Float16)a1.z, (_Float16)a1.w };
#pragma unroll
        for (int ct = 0; ct < 8; ++ct) {
            half8_t bf = *(const half8_t*)(w1t + (ct * 16 + mn) * 128 + kk * 32 + quad * 8);
            acc[ct] = __builtin_amdgcn_mfma_f32_16x16x32_f16(af, bf, acc[ct], 0, 0, 0);
        }
    }
    // C layout: col = lane&15, row = quad*4 + reg -> LDS (2-way banks max)
#pragma unroll
    for (int ct = 0; ct < 8; ++ct)
#pragma unroll
        for (int r = 0; r < 4; ++r) {
            int nl = wv * 16 + quad * 4 + r;
            sm.cs[nl * 136 + ct * 16 + mn] = (_Float16)acc[ct][r];
        }
    __syncthreads();
    // epilogue: thread (node=t>>2, seg=t&3): 64B h-row segment -> global + logits
    int node = t >> 2, seg = t & 3;
    int gn = nb + node;
    if (gn < N_NODES) {
        const half8_t* hp = (const half8_t*)&sm.cs[node * 136 + seg * 32];
        uint4* gout = (uint4*)(h1h + (size_t)gn * 128 + seg * 32);
        const float4* asp = (const float4*)a_src;
        const float4* adp = (const float4*)a_dst;
        float vs = 0.f, vd = 0.f;
#pragma unroll
        for (int jj = 0; jj < 4; ++jj) {
            half8_t hv = hp[jj];
            gout[jj] = *(const uint4*)&hv;
            float4 aS0 = asp[seg * 8 + jj * 2], aS1 = asp[seg * 8 + jj * 2 + 1];
            float4 aD0 = adp[seg * 8 + jj * 2], aD1 = adp[seg * 8 + jj * 2 + 1];
            vs += (float)hv[0] * aS0.x + (float)hv[1] * aS0.y + (float)hv[2] * aS0.z + (float)hv[3] * aS0.w
                + (float)hv[4] * aS1.x + (float)hv[5] * aS1.y + (float)hv[6] * aS1.z + (float)hv[7] * aS1.w;
            vd += (float)hv[0] * aD0.x + (float)hv[1] * aD0.y + (float)hv[2] * aD0.z + (float)hv[3] * aD0.w
                + (float)hv[4] * aD1.x + (float)hv[5] * aD1.y + (float)hv[6] * aD1.z + (float)hv[7] * aD1.w;
        }
        als[gn * 4 + seg] = vs;
        ald[gn * 4 + seg] = vd;
    }
}

// ---- Layer 1 aggregation: wave/node, 4 edges/iter uint4 row gathers ----
__global__ __launch_bounds__(256) void k_agg1(const unsigned short* __restrict__ h1h,
                                              const float* __restrict__ als,
                                              const float* __restrict__ ald,
                                              const int* __restrict__ rowptr,
                                              const int* __restrict__ deg,
                                              const int* __restrict__ col,
                                              const float* __restrict__ b1,
                                              float* __restrict__ out1) {
    __shared__ float sex_all[4][64 * 4];
    __shared__ int   scol_all[4][64];
    int w = threadIdx.x >> 6;
    int lane = threadIdx.x & 63;
    int n = blockIdx.x * 4 + w;
    int slot = lane >> 4, cg = lane & 15;
    int hd = cg >> 2;
    float* sex = sex_all[w];
    int* scol = scol_all[w];
    float4 ald4 = ((const float4*)ald)[n];
    int beg = rowptr[n], dtot = deg[n];
    float a0 = 0.f, a1 = 0.f, a2 = 0.f, a3 = 0.f;
    float a4 = 0.f, a5 = 0.f, a6 = 0.f, a7 = 0.f, den = 0.f;
    const float4* als4p = (const float4*)als;
    for (int base = 0; base < dtot; base += 64) {
        int cnt = min(64, dtot - base);
        int myc = 0;
        if (lane < cnt) myc = col[beg + base + lane];
        __asm__ volatile("s_waitcnt lgkmcnt(0)" ::: "memory");
        if (lane < cnt) {
            scol[lane] = myc;
            float4 as4 = als4p[myc];
            float4 e4;
            e4.x = __expf(lrelu(as4.x + ald4.x));
            e4.y = __expf(lrelu(as4.y + ald4.y));
            e4.z = __expf(lrelu(as4.z + ald4.z));
            e4.w = __expf(lrelu(as4.w + ald4.w));
            ((float4*)sex)[lane] = e4;
        }
        __asm__ volatile("s_waitcnt lgkmcnt(0)" ::: "memory");
#pragma unroll 2
        for (int q4 = 0; q4 < cnt; q4 += 4) {
            int myq = q4 + slot;
            int cq = min(myq, cnt - 1);
            int s = scol[cq];
            float ex = (myq < cnt) ? sex[cq * 4 + hd] : 0.f;
            uint4 hv = *(const uint4*)((const char*)h1h + (((size_t)s << 8) + (cg << 4)));
            a0 = fmaf(ex, f16lo(hv.x), a0);
            a1 = fmaf(ex, f16hi(hv.x), a1);
            a2 = fmaf(ex, f16lo(hv.y), a2);
            a3 = fmaf(ex, f16hi(hv.y), a3);
            a4 = fmaf(ex, f16lo(hv.z), a4);
            a5 = fmaf(ex, f16hi(hv.z), a5);
            a6 = fmaf(ex, f16lo(hv.w), a6);
            a7 = fmaf(ex, f16hi(hv.w), a7);
            den += ex;
        }
    }
    a0 += __shfl_xor(a0, 16, 64); a1 += __shfl_xor(a1, 16, 64);
    a2 += __shfl_xor(a2, 16, 64); a3 += __shfl_xor(a3, 16, 64);
    a4 += __shfl_xor(a4, 16, 64); a5 += __shfl_xor(a5, 16, 64);
    a6 += __shfl_xor(a6, 16, 64); a7 += __shfl_xor(a7, 16, 64);
    den += __shfl_xor(den, 16, 64);
    a0 += __shfl_xor(a0, 32, 64); a1 += __shfl_xor(a1, 32, 64);
    a2 += __shfl_xor(a2, 32, 64); a3 += __shfl_xor(a3, 32, 64);
    a4 += __shfl_xor(a4, 32, 64); a5 += __shfl_xor(a5, 32, 64);
    a6 += __shfl_xor(a6, 32, 64); a7 += __shfl_xor(a7, 32, 64);
    den += __shfl_xor(den, 32, 64);
    if (lane < 16) {
        float inv = 1.0f / den;
        float4 bA = ((const float4*)b1)[2 * lane];
        float4 bB = ((const float4*)b1)[2 * lane + 1];
        float4 oA, oB;
        oA.x = fmaxf(fmaf(a0, inv, bA.x), 0.f);
        oA.y = fmaxf(fmaf(a1, inv, bA.y), 0.f);
        oA.z = fmaxf(fmaf(a2, inv, bA.z), 0.f);
        oA.w = fmaxf(fmaf(a3, inv, bA.w), 0.f);
        oB.x = fmaxf(fmaf(a4, inv, bB.x), 0.f);
        oB.y = fmaxf(fmaf(a5, inv, bB.y), 0.f);
        oB.z = fmaxf(fmaf(a6, inv, bB.z), 0.f);
        oB.w = fmaxf(fmaf(a7, inv, bB.w), 0.f);
        ((float4*)out1)[(size_t)n * 32 + 2 * lane]     = oA;
        ((float4*)out1)[(size_t)n * 32 + 2 * lane + 1] = oB;
    }
}

// ---- Layer 2 GEMM: h2(fp16) = out1 @ W2, fused logits ----
__global__ __launch_bounds__(256) void k_gemm2(const float* __restrict__ out1,
                                               const float* __restrict__ W2,
                                               const float* __restrict__ a_src,
                                               const float* __restrict__ a_dst,
                                               unsigned short* __restrict__ h2h,
                                               float* __restrict__ als,
                                               float* __restrict__ ald) {
    __shared__ float W2s[128 * 16];
    __shared__ float xs[16 * 132];
    int t = threadIdx.x;
#pragma unroll
    for (int i = 0; i < 8; ++i) W2s[t + i * 256] = W2[t + i * 256];
    size_t base = (size_t)blockIdx.x * 16 * 128;
#pragma unroll
    for (int i = 0; i < 8; ++i) {
        int idx = t + i * 256;
        xs[(idx >> 7) * 132 + (idx & 127)] = out1[base + idx];
    }
    __syncthreads();
    int r = t >> 4, c = t & 15;
    float acc = 0.f;
    const float* xr = &xs[r * 132];
#pragma unroll 8
    for (int k = 0; k < 128; ++k) acc = fmaf(xr[k], W2s[k * 16 + c], acc);
    int n = blockIdx.x * 16 + r;
    h2h[(size_t)n * 16 + c] = __half_as_ushort(__float2half(acc));
    float vs = acc * a_src[c];
    float vd = acc * a_dst[c];
#pragma unroll
    for (int off = 8; off >= 1; off >>= 1) {
        vs += __shfl_down(vs, off, 16);
        vd += __shfl_down(vd, off, 16);
    }
    if (c == 0) { als[n] = vs; ald[n] = vd; }
}

// ---- Layer 2 aggregation: wave/node, 16 edges/iter, batched exp in LDS ----
__global__ __launch_bounds__(256) void k_agg2(const unsigned short* __restrict__ h2h,
                                              const float* __restrict__ als,
                                              const float* __restrict__ ald,
                                              const int* __restrict__ rowptr,
                                              const int* __restrict__ deg,
                                              const int* __restrict__ col,
                                              const float* __restrict__ b2,
                                              float* __restrict__ out) {
    __shared__ float sex_all[4][64];
    __shared__ int   scol_all[4][64];
    int w = threadIdx.x >> 6;
    int lane = threadIdx.x & 63;
    int n = blockIdx.x * 4 + w;
    int slot = lane >> 2, q = lane & 3;
    float* sex = sex_all[w];
    int* scol = scol_all[w];
    float ad = ald[n];
    int beg = rowptr[n], dtot = deg[n];
    float a0 = 0.f, a1 = 0.f, a2 = 0.f, a3 = 0.f, den = 0.f;
    for (int base = 0; base < dtot; base += 64) {
        int cnt = min(64, dtot - base);
        int myc = 0;
        if (lane < cnt) myc = col[beg + base + lane];
        __asm__ volatile("s_waitcnt lgkmcnt(0)" ::: "memory");
        if (lane < cnt) {
            scol[lane] = myc;
            sex[lane] = __expf(lrelu(als[myc] + ad));
        }
        __asm__ volatile("s_waitcnt lgkmcnt(0)" ::: "memory");
#pragma unroll 2
        for (int q16 = 0; q16 < cnt; q16 += 16) {
            int myq = q16 + slot;
            int cq = min(myq, cnt - 1);
            int s = scol[cq];
            float ex = (myq < cnt) ? sex[cq] : 0.f;
            uint2 hv = *(const uint2*)((const char*)h2h + ((size_t)s * 32u + (q << 3)));
            a0 = fmaf(ex, f16lo(hv.x), a0);
            a1 = fmaf(ex, f16hi(hv.x), a1);
            a2 = fmaf(ex, f16lo(hv.y), a2);
            a3 = fmaf(ex, f16hi(hv.y), a3);
            den += ex;
        }
    }
#pragma unroll
    for (int off = 4; off <= 32; off <<= 1) {
        a0 += __shfl_xor(a0, off, 64);
        a1 += __shfl_xor(a1, off, 64);
        a2 += __shfl_xor(a2, off, 64);
        a3 += __shfl_xor(a3, off, 64);
        den += __shfl_xor(den, off, 64);
    }
    if (slot == 0) {
        float inv = 1.0f / den;
        float4 b4 = ((const float4*)b2)[q];
        float4 o;
        o.x = fmaf(a0, inv, b4.x);
        o.y = fmaf(a1, inv, b4.y);
        o.z = fmaf(a2, inv, b4.z);
        o.w = fmaf(a3, inv, b4.w);
        ((float4*)out)[(size_t)n * 4 + q] = o;
    }
}

extern "C" void kernel_launch(void* const* d_in, const int* in_sizes, int n_in,
                              void* d_out, int out_size, void* d_ws, size_t ws_size,
                              hipStream_t stream) {
    const float* x   = (const float*)d_in[0];
    const int*   ei  = (const int*)d_in[1];
    const float* W1  = (const float*)d_in[2];
    const float* as1 = (const float*)d_in[3];
    const float* ad1 = (const float*)d_in[4];
    const float* b1  = (const float*)d_in[5];
    const float* W2  = (const float*)d_in[6];
    const float* as2 = (const float*)d_in[7];
    const float* ad2 = (const float*)d_in[8];
    const float* b2  = (const float*)d_in[9];
    float* out = (float*)d_out;

    char* ws = (char*)d_ws;
    size_t off = 0;
    auto alloc = [&](size_t bytes) -> void* {
        void* p = ws + off;
        off += (bytes + 255) & ~(size_t)255;
        return p;
    };
    unsigned short* h1h = (unsigned short*)alloc((size_t)N_NODES * 128 * 2);
    float* out1  = (float*)alloc((size_t)N_NODES * 128 * 4);
    float* als1v = (float*)alloc((size_t)N_NODES * 4 * 4);
    float* ald1v = (float*)alloc((size_t)N_NODES * 4 * 4);
    unsigned short* h2h = (unsigned short*)alloc((size_t)N_NODES * 16 * 2);
    float* als2v = (float*)alloc((size_t)N_NODES * 4);
    float* ald2v = (float*)alloc((size_t)N_NODES * 4);
    int* rowptr  = (int*)alloc((size_t)N_NODES * 4);
    int* degv    = (int*)alloc((size_t)N_NODES * 4);
    int* gcur    = (int*)alloc((size_t)NBKT * GSTRIDE * 4);
    _Float16* w1t = (_Float16*)alloc((size_t)128 * 128 * 2);
    int* packed  = (int*)alloc((size_t)NBKT * CAP * 4);
    int* colA    = (int*)alloc((size_t)NBKT * CAP * 4);

    hipMemsetAsync(gcur, 0, (size_t)NBKT * GSTRIDE * 4, stream);
    k_prep_part<<<PREP_B + PART_B, 256, 0, stream>>>(W1, w1t, ei, gcur, packed);
    k_gemm1_build<<<NBKT + GEMM1_B, 256, 0, stream>>>(x, w1t, as1, ad1, h1h, als1v, ald1v,
                                                      packed, gcur, rowptr, degv, colA);
    k_agg1<<<N_NODES / 4, 256, 0, stream>>>(h1h, als1v, ald1v, rowptr, degv, colA, b1, out1);
    k_gemm2<<<N_NODES / 16, 256, 0, stream>>>(out1, W2, as2, ad2, h2h, als2v, ald2v);
    k_agg2<<<N_NODES / 4, 256, 0, stream>>>(h2h, als2v, ald2v, rowptr, degv, colA, b2, out);
}